// Round 1
// baseline (1868.879 us; speedup 1.0000x reference)
//
#include <hip/hip_runtime.h>
#include <math.h>

#define B_  256
#define T_  48
#define D_  89
#define H_  128
#define C_  64
#define FF_ 64
#define NH_ 8
#define HD_ 8
#define N2T 96   // 2*T

// output layout (floats)
#define XIMP_OFF 0
#define LOSS_OFF 1093632
#define HID_OFF  1093633
#define Y_OFF    2666497
#define YS_OFF   2666753

__device__ __forceinline__ float wave_sum64(float v) {
    v += __shfl_xor(v, 32);
    v += __shfl_xor(v, 16);
    v += __shfl_xor(v, 8);
    v += __shfl_xor(v, 4);
    v += __shfl_xor(v, 2);
    v += __shfl_xor(v, 1);
    return v;
}

// ---------------- Phase A: decay factor + time encoder + positional encoding
// one block per (b,t); 128 threads.
__global__ void k_phaseA(const float* __restrict__ last_obs,
                         const float* __restrict__ deltas,
                         const float* __restrict__ medians,
                         const float* __restrict__ W_wo, const float* __restrict__ b_wo,
                         const float* __restrict__ W_inp, const float* __restrict__ b_inp,
                         float* __restrict__ data) {
    int bt = blockIdx.x;
    int b = bt / T_;
    int t = bt - b * T_;
    __shared__ float dd[D_], lo[D_], dec[D_];
    int tid = threadIdx.x;
    int base = (b * T_ + t) * D_;
    if (tid < D_) {
        float dv = deltas[base + tid] - medians[tid];
        dd[tid] = dv;
        lo[tid] = last_obs[base + tid];
    }
    __syncthreads();
    if (tid < D_) {
        const float* wr = W_wo + tid * D_;
        float acc = b_wo[tid];
        for (int j = 0; j < D_; ++j) acc = fmaf(dd[j], wr[j], acc);
        float dv = dd[tid];
        float s = (dv > 0.f) ? 1.f : ((dv < 0.f) ? -1.f : 0.f);
        dec[tid] = 0.5f * (1.f - tanhf(s * fabsf(acc)));
    }
    __syncthreads();
    int c = tid & 63;
    int half = tid >> 6;            // 0: last_obs proj, 1: decay proj
    const float* src = half ? dec : lo;
    const float* wr = W_inp + c * D_;
    float acc = b_inp[c];
    for (int j = 0; j < D_; ++j) acc = fmaf(src[j], wr[j], acc);
    // positional encoding pe[t, c]
    int i = c >> 1;
    float div = expf((float)i * -0.28782313662425574f); // exp(2i * -ln(10000)/64)
    float ang = (float)t * div;
    float pe = (c & 1) ? cosf(ang) : sinf(ang);
    data[((b * N2T) + half * T_ + t) * C_ + c] = acc + pe;
}

// ---------------- qkv projection: one block per (b,n); 192 threads.
__global__ void k_qkv(const float* __restrict__ data,
                      const float* __restrict__ attn_in_w, const float* __restrict__ attn_in_b,
                      float* __restrict__ qkv) {
    int bn = blockIdx.x;
    __shared__ float row[C_];
    int tid = threadIdx.x;
    if (tid < C_) row[tid] = data[bn * C_ + tid];
    __syncthreads();
    const float* wr = attn_in_w + tid * C_;
    float acc = attn_in_b[tid];
    for (int j = 0; j < C_; ++j) acc = fmaf(row[j], wr[j], acc);
    qkv[bn * 192 + tid] = acc;
}

// ---------------- attention: one block per (n,h); 256 threads (thread = s over B).
__global__ void k_attn(const float* __restrict__ qkv, float* __restrict__ attnO) {
    int n = blockIdx.x >> 3;
    int h = blockIdx.x & 7;
    __shared__ float k_lds[B_][HD_ + 1];
    __shared__ float v_lds[B_][HD_ + 1];
    int s = threadIdx.x;
    const float scale = 0.35355339059327373f; // 1/sqrt(8)
    float q[HD_];
    const float* qp = qkv + ((size_t)s * N2T + n) * 192 + h * HD_;
    #pragma unroll
    for (int d = 0; d < HD_; ++d) q[d] = qp[d] * scale;
    const float* kp = qp + 64;
    const float* vp = qp + 128;
    #pragma unroll
    for (int d = 0; d < HD_; ++d) { k_lds[s][d] = kp[d]; v_lds[s][d] = vp[d]; }
    __syncthreads();
    // pass 1: max
    float m = -1e30f;
    for (int t = 0; t < B_; ++t) {
        float sc = 0.f;
        #pragma unroll
        for (int d = 0; d < HD_; ++d) sc = fmaf(q[d], k_lds[t][d], sc);
        m = fmaxf(m, sc);
    }
    // pass 2: exp + accumulate
    float l = 0.f;
    float acc[HD_] = {0.f, 0.f, 0.f, 0.f, 0.f, 0.f, 0.f, 0.f};
    for (int t = 0; t < B_; ++t) {
        float sc = 0.f;
        #pragma unroll
        for (int d = 0; d < HD_; ++d) sc = fmaf(q[d], k_lds[t][d], sc);
        float p = __expf(sc - m);
        l += p;
        #pragma unroll
        for (int d = 0; d < HD_; ++d) acc[d] = fmaf(p, v_lds[t][d], acc[d]);
    }
    float inv = 1.f / l;
    float* op = attnO + ((size_t)s * N2T + n) * C_ + h * HD_;
    #pragma unroll
    for (int d = 0; d < HD_; ++d) op[d] = acc[d] * inv;
}

// ---------------- transformer post-attn: out proj + LN1 + FF(gelu) + LN2 + op1
// one block per (b,n); 64 threads (one wave).
__global__ void k_transform(const float* __restrict__ data,
                            const float* __restrict__ attnO,
                            const float* __restrict__ attn_out_w, const float* __restrict__ attn_out_b,
                            const float* __restrict__ ln1_g, const float* __restrict__ ln1_b,
                            const float* __restrict__ ff1_w, const float* __restrict__ ff1_b,
                            const float* __restrict__ ff2_w, const float* __restrict__ ff2_b,
                            const float* __restrict__ ln2_g, const float* __restrict__ ln2_b,
                            const float* __restrict__ W_op1, const float* __restrict__ b_op1,
                            float* __restrict__ val) {
    int bn = blockIdx.x;
    __shared__ float orow[C_], x1s[C_], hbuf[C_], x2s[C_];
    int c = threadIdx.x;
    float d0 = data[bn * C_ + c];
    orow[c] = attnO[bn * C_ + c];
    __syncthreads();
    float acc = attn_out_b[c];
    {
        const float* wr = attn_out_w + c * C_;
        for (int j = 0; j < C_; ++j) acc = fmaf(orow[j], wr[j], acc);
    }
    float r = d0 + acc;
    // LN1 across the wave
    float mean = wave_sum64(r) * (1.f / 64.f);
    float df = r - mean;
    float var = wave_sum64(df * df) * (1.f / 64.f);
    float x1 = df * rsqrtf(var + 1e-5f) * ln1_g[c] + ln1_b[c];
    x1s[c] = x1;
    __syncthreads();
    // FF1 + gelu (exact)
    acc = ff1_b[c];
    {
        const float* wr = ff1_w + c * C_;
        for (int j = 0; j < C_; ++j) acc = fmaf(x1s[j], wr[j], acc);
    }
    float ge = 0.5f * acc * (1.f + erff(acc * 0.7071067811865475f));
    hbuf[c] = ge;
    __syncthreads();
    // FF2
    acc = ff2_b[c];
    {
        const float* wr = ff2_w + c * C_;
        for (int j = 0; j < C_; ++j) acc = fmaf(hbuf[j], wr[j], acc);
    }
    float r2 = x1 + acc;
    // LN2
    float mean2 = wave_sum64(r2) * (1.f / 64.f);
    float df2 = r2 - mean2;
    float var2 = wave_sum64(df2 * df2) * (1.f / 64.f);
    float x2 = df2 * rsqrtf(var2 + 1e-5f) * ln2_g[c] + ln2_b[c];
    x2s[c] = x2;
    __syncthreads();
    // op1: this thread produces outputs c and c+64
    #pragma unroll
    for (int rep = 0; rep < 2; ++rep) {
        int k = c + rep * 64;
        float a2 = b_op1[k];
        const float* wr = W_op1 + k * C_;
        for (int j = 0; j < C_; ++j) a2 = fmaf(x2s[j], wr[j], a2);
        val[(size_t)bn * H_ + k] = a2;
    }
}

// ---------------- h0 = conv1d over n (96 -> 1): one block per b; 128 threads (h).
__global__ void k_reduce_h0(const float* __restrict__ val,
                            const float* __restrict__ W_op2, const float* __restrict__ b_op2,
                            float* __restrict__ h0) {
    int b = blockIdx.x;
    int h = threadIdx.x;
    float acc = b_op2[0];
    for (int n = 0; n < N2T; ++n)
        acc = fmaf(val[((size_t)b * N2T + n) * H_ + h], W_op2[n], acc);
    h0[b * H_ + h] = acc;
}

// ---------------- per-step mask denominator: one block per t; 256 threads.
__global__ void k_den(const float* __restrict__ mask, float* __restrict__ den) {
    int t = blockIdx.x;
    int tid = threadIdx.x;
    float s = 0.f;
    const int total = B_ * D_;
    for (int i = tid; i < total; i += 256) {
        int b = i / D_;
        int d = i - b * D_;
        s += mask[(b * T_ + t) * D_ + d];
    }
    s = wave_sum64(s);
    __shared__ float red[4];
    if ((tid & 63) == 0) red[tid >> 6] = s;
    __syncthreads();
    if (tid == 0) den[t] = red[0] + red[1] + red[2] + red[3];
}

// ---------------- the recurrent scan: one block per batch element; 256 threads.
__global__ __launch_bounds__(256)
void k_scan(const float* __restrict__ x, const float* __restrict__ mask,
            const float* __restrict__ deltas,
            const float* __restrict__ W_dh, const float* __restrict__ b_dh,
            const float* __restrict__ W_dx, const float* __restrict__ b_dx,
            const float* __restrict__ W_hist, const float* __restrict__ b_hist,
            const float* __restrict__ W_feat, const float* __restrict__ b_feat,
            const float* __restrict__ W_wc, const float* __restrict__ b_wc,
            const float* __restrict__ W_ih, const float* __restrict__ W_hh,
            const float* __restrict__ b_ih, const float* __restrict__ b_hh,
            const float* __restrict__ W_cls, const float* __restrict__ b_cls,
            const float* __restrict__ h0,
            float* __restrict__ out_ximp, float* __restrict__ out_hid,
            float* __restrict__ out_y, float* __restrict__ out_ys,
            float* __restrict__ num_part) {
    int b = blockIdx.x;
    int tid = threadIdx.x;
    __shared__ float h[H_];
    __shared__ float xt[D_], mt[D_], dt[D_];
    __shared__ float xh[D_], xr[D_], gx[D_], ximp[D_], diffb[D_];
    __shared__ float gi[384], gh[384];

    if (tid < H_) h[tid] = h0[b * H_ + tid];

    for (int t = 0; t < T_; ++t) {
        int base = (b * T_ + t) * D_;
        if (tid < D_) {
            xt[tid] = x[base + tid];
            mt[tid] = mask[base + tid];
            dt[tid] = deltas[base + tid];
        }
        __syncthreads();
        // gamma_h and decay h
        if (tid < H_) {
            const float* wr = W_dh + tid * D_;
            float acc = b_dh[tid];
            for (int j = 0; j < D_; ++j) acc = fmaf(dt[j], wr[j], acc);
            h[tid] *= expf(-fmaxf(acc, 0.f));
        }
        __syncthreads();
        // x_h, x_r, gamma_x
        if (tid < D_) {
            const float* wr = W_hist + tid * H_;
            float acc = b_hist[tid];
            for (int j = 0; j < H_; ++j) acc = fmaf(h[j], wr[j], acc);
            xh[tid] = acc;
            float m = mt[tid];
            xr[tid] = m * xt[tid] + (1.f - m) * acc;
            gx[tid] = expf(-fmaxf(dt[tid] * W_dx[tid * D_ + tid] + b_dx[tid], 0.f));
        }
        __syncthreads();
        // xu (off-diag), beta, x_comb, loss term, x_imp
        if (tid < D_) {
            const float* wf = W_feat + tid * D_;
            float xu = b_feat[tid];
            for (int j = 0; j < D_; ++j)
                if (j != tid) xu = fmaf(xr[j], wf[j], xu);
            const float* wc = W_wc + tid * 178;
            float beta = b_wc[tid];
            for (int j = 0; j < D_; ++j) beta = fmaf(gx[j], wc[j], beta);
            for (int j = 0; j < D_; ++j) beta = fmaf(mt[j], wc[D_ + j], beta);
            float xc = beta * xu + (1.f - beta) * xh[tid];
            float m = mt[tid];
            float xi = m * xt[tid] + (1.f - m) * xc;
            ximp[tid] = xi;
            out_ximp[XIMP_OFF + base + tid] = xi;
            diffb[tid] = fabsf(xt[tid] - xc) * m;
        }
        __syncthreads();
        if (tid == 0) {
            float s = 0.f;
            for (int j = 0; j < D_; ++j) s += diffb[j];
            num_part[t * B_ + b] = s;
        }
        // gi (384 outs over concat[x_imp, m]) and gh (384 outs over h)
        {
            int k = tid;
            const float* wr = W_ih + (size_t)k * 178;
            float acc = b_ih[k];
            for (int j = 0; j < D_; ++j) acc = fmaf(ximp[j], wr[j], acc);
            for (int j = 0; j < D_; ++j) acc = fmaf(mt[j], wr[D_ + j], acc);
            gi[k] = acc;
            const float* wh = W_hh + (size_t)k * H_;
            float ach = b_hh[k];
            for (int j = 0; j < H_; ++j) ach = fmaf(h[j], wh[j], ach);
            gh[k] = ach;
        }
        if (tid < H_) {
            int k = 256 + tid;
            const float* wr = W_ih + (size_t)k * 178;
            float acc = b_ih[k];
            for (int j = 0; j < D_; ++j) acc = fmaf(ximp[j], wr[j], acc);
            for (int j = 0; j < D_; ++j) acc = fmaf(mt[j], wr[D_ + j], acc);
            gi[k] = acc;
            const float* wh = W_hh + (size_t)k * H_;
            float ach = b_hh[k];
            for (int j = 0; j < H_; ++j) ach = fmaf(h[j], wh[j], ach);
            gh[k] = ach;
        }
        __syncthreads();
        // GRU update
        if (tid < H_) {
            float r = 1.f / (1.f + expf(-(gi[tid] + gh[tid])));
            float z = 1.f / (1.f + expf(-(gi[H_ + tid] + gh[H_ + tid])));
            float g = tanhf(gi[2 * H_ + tid] + r * gh[2 * H_ + tid]);
            float hn = (1.f - z) * g + z * h[tid];
            h[tid] = hn;
            out_hid[HID_OFF + (size_t)(b * T_ + t) * H_ + tid] = hn;
        }
        __syncthreads();
    }
    // classifier
    if (tid == 0) {
        float acc = b_cls[0];
        for (int j = 0; j < H_; ++j) acc = fmaf(h[j], W_cls[j], acc);
        out_y[Y_OFF + b] = acc;
        out_ys[YS_OFF + b] = 1.f / (1.f + expf(-acc));
    }
}

// ---------------- final loss reduction: 1 block, 64 threads.
__global__ void k_loss(const float* __restrict__ num_part, const float* __restrict__ den,
                       float* __restrict__ out) {
    int tid = threadIdx.x;
    float v = 0.f;
    if (tid < T_) {
        float s = 0.f;
        const float* np_ = num_part + tid * B_;
        for (int b = 0; b < B_; ++b) s += np_[b];
        v = s / (den[tid] + 1e-5f);
    }
    v = wave_sum64(v);
    if (tid == 0) out[LOSS_OFF] = v;
}

extern "C" void kernel_launch(void* const* d_in, const int* in_sizes, int n_in,
                              void* d_out, int out_size, void* d_ws, size_t ws_size,
                              hipStream_t stream) {
    const float* x        = (const float*)d_in[0];
    const float* mask     = (const float*)d_in[1];
    const float* deltas   = (const float*)d_in[2];
    const float* last_obs = (const float*)d_in[3];
    const float* medians  = (const float*)d_in[4];
    const float* W_dh  = (const float*)d_in[5];
    const float* b_dh  = (const float*)d_in[6];
    const float* W_dx  = (const float*)d_in[7];
    const float* b_dx  = (const float*)d_in[8];
    const float* W_hist= (const float*)d_in[9];
    const float* b_hist= (const float*)d_in[10];
    const float* W_feat= (const float*)d_in[11];
    const float* b_feat= (const float*)d_in[12];
    const float* W_wc  = (const float*)d_in[13];
    const float* b_wc  = (const float*)d_in[14];
    const float* W_wo  = (const float*)d_in[15];
    const float* b_wo  = (const float*)d_in[16];
    const float* W_cls = (const float*)d_in[17];
    const float* b_cls = (const float*)d_in[18];
    const float* W_ih  = (const float*)d_in[19];
    const float* W_hh  = (const float*)d_in[20];
    const float* b_ih  = (const float*)d_in[21];
    const float* b_hh  = (const float*)d_in[22];
    const float* W_inp = (const float*)d_in[23];
    const float* b_inp = (const float*)d_in[24];
    const float* W_op1 = (const float*)d_in[25];
    const float* b_op1 = (const float*)d_in[26];
    const float* W_op2 = (const float*)d_in[27];
    const float* b_op2 = (const float*)d_in[28];
    const float* attn_in_w  = (const float*)d_in[29];
    const float* attn_in_b  = (const float*)d_in[30];
    const float* attn_out_w = (const float*)d_in[31];
    const float* attn_out_b = (const float*)d_in[32];
    const float* ln1_g = (const float*)d_in[33];
    const float* ln1_b = (const float*)d_in[34];
    const float* ln2_g = (const float*)d_in[35];
    const float* ln2_b = (const float*)d_in[36];
    const float* ff1_w = (const float*)d_in[37];
    const float* ff1_b = (const float*)d_in[38];
    const float* ff2_w = (const float*)d_in[39];
    const float* ff2_b = (const float*)d_in[40];

    float* out = (float*)d_out;

    // workspace layout (floats)
    float* ws = (float*)d_ws;
    float* data  = ws;                        // B*96*64      = 1,572,864
    float* qkv   = data  + (size_t)B_ * N2T * C_;      // B*96*192 = 4,718,592
    float* attnO = qkv   + (size_t)B_ * N2T * 192;     // B*96*64  = 1,572,864
    float* val   = attnO + (size_t)B_ * N2T * C_;      // B*96*128 = 3,145,728
    float* h0    = val   + (size_t)B_ * N2T * H_;      // B*128    = 32,768
    float* den   = h0    + (size_t)B_ * H_;            // 48
    float* nump  = den   + T_;                         // 48*256   = 12,288

    k_phaseA<<<B_ * T_, 128, 0, stream>>>(last_obs, deltas, medians, W_wo, b_wo, W_inp, b_inp, data);
    k_qkv<<<B_ * N2T, 192, 0, stream>>>(data, attn_in_w, attn_in_b, qkv);
    k_attn<<<N2T * NH_, 256, 0, stream>>>(qkv, attnO);
    k_transform<<<B_ * N2T, 64, 0, stream>>>(data, attnO, attn_out_w, attn_out_b,
                                             ln1_g, ln1_b, ff1_w, ff1_b, ff2_w, ff2_b,
                                             ln2_g, ln2_b, W_op1, b_op1, val);
    k_reduce_h0<<<B_, H_, 0, stream>>>(val, W_op2, b_op2, h0);
    k_den<<<T_, 256, 0, stream>>>(mask, den);
    k_scan<<<B_, 256, 0, stream>>>(x, mask, deltas,
                                   W_dh, b_dh, W_dx, b_dx, W_hist, b_hist, W_feat, b_feat,
                                   W_wc, b_wc, W_ih, W_hh, b_ih, b_hh, W_cls, b_cls,
                                   h0, out, out, out, out, nump);
    k_loss<<<1, 64, 0, stream>>>(nump, den, out);
}